// Round 1
// baseline (4280.631 us; speedup 1.0000x reference)
//
#include <hip/hip_runtime.h>
#include <math.h>

// Problem dims
#define B_   256
#define T_   512
#define F_   64
#define H1_  100
#define H2_  128
#define OUT_ 19
#define G1_  400   // 4*H1
#define G2_  512   // 4*H2
#define TC   64    // timesteps per chunk
#define NCHUNK (T_/TC)

// ---- LDS layout (in floats) ----
// Union region [0, 32768):
//   during A0/A1: xs[TC*F_]=4096 at 0, xp1[TC*G1_]=25600 at 4096 (ends 29696)
//   during A2/B : xp2[TC*G2_]=32768 at 0
#define OFF_XS    0
#define OFF_XP1   (TC*F_)                 // 4096
#define OFF_XP2   0
#define OFF_H1C   32768                   // TC*H1_ = 6400 floats
#define OFF_ZBUF  (OFF_H1C + TC*H1_)      // 39168, 512 floats
#define OFF_H1S   (OFF_ZBUF + G2_)        // 39680, 128 floats (100 used)
#define OFF_H2S   (OFF_H1S + 128)         // 39808, 128 floats
#define LDS_FLOATS (OFF_H2S + 128)        // 39936 floats = 159744 B (<=163840)

__device__ __forceinline__ float sigm(float x) {
    return 1.0f / (1.0f + __expf(-x));
}

__global__ __launch_bounds__(512, 2) void lstm_fused(
    const float* __restrict__ x,
    const float* __restrict__ W1, const float* __restrict__ U1, const float* __restrict__ b1,
    const float* __restrict__ W2, const float* __restrict__ U2, const float* __restrict__ b2,
    const float* __restrict__ Wd, const float* __restrict__ bd,
    float* __restrict__ out)
{
    __shared__ float lds[LDS_FLOATS];
    const int b = blockIdx.x;
    const int j = threadIdx.x;

    float wr[128];          // per-phase weight column (max 128 floats)
    float c1 = 0.0f;        // cell state, thread k<100 owns c1[k]
    float c2 = 0.0f;        // cell state, thread k<128 owns c2[k]

    if (j < 128) { lds[OFF_H1S + j] = 0.0f; lds[OFF_H2S + j] = 0.0f; }
    __syncthreads();

    const float* xrow = x + (size_t)b * T_ * F_;

    for (int ch = 0; ch < NCHUNK; ++ch) {
        const int t0 = ch * TC;

        // ---- stage x chunk: TC*F_ = 4096 floats, coalesced ----
        {
            const float* src = xrow + t0 * F_;
            #pragma unroll
            for (int r = 0; r < (TC * F_) / 512; ++r)
                lds[OFF_XS + r * 512 + j] = src[r * 512 + j];
        }
        // ---- load W1 column j (coalesced across threads) ----
        if (j < G1_) {
            #pragma unroll
            for (int k = 0; k < F_; ++k) wr[k] = W1[k * G1_ + j];
        }
        __syncthreads();   // xs staged (also: prev chunk's B reads of xp2 done before we wrote xs)

        // ---- A0: xp1[t][j] = b1[j] + x_t . W1col_j  (dense, barrier-free) ----
        if (j < G1_) {
            const float bj = b1[j];
            for (int t = 0; t < TC; ++t) {
                const float4* xs4 = (const float4*)&lds[OFF_XS + t * F_];
                float acc = bj;
                #pragma unroll
                for (int k = 0; k < F_ / 4; ++k) {
                    float4 v = xs4[k];
                    acc += v.x * wr[4*k] + v.y * wr[4*k+1] + v.z * wr[4*k+2] + v.w * wr[4*k+3];
                }
                lds[OFF_XP1 + t * G1_ + j] = acc;
            }
            // swap in U1 column j for the recurrence
            #pragma unroll
            for (int k = 0; k < H1_; ++k) wr[k] = U1[k * G1_ + j];
        }
        __syncthreads();

        // ---- A1: layer-1 recurrence over the chunk ----
        for (int t = 0; t < TC; ++t) {
            if (j < G1_) {
                float acc = lds[OFF_XP1 + t * G1_ + j];
                const float4* h4 = (const float4*)&lds[OFF_H1S];
                #pragma unroll
                for (int k = 0; k < H1_ / 4; ++k) {
                    float4 v = h4[k];
                    acc += v.x * wr[4*k] + v.y * wr[4*k+1] + v.z * wr[4*k+2] + v.w * wr[4*k+3];
                }
                lds[OFF_ZBUF + j] = acc;
            }
            __syncthreads();
            if (j < H1_) {
                float zi = lds[OFF_ZBUF + j];
                float zf = lds[OFF_ZBUF + H1_ + j];
                float zg = lds[OFF_ZBUF + 2 * H1_ + j];
                float zo = lds[OFF_ZBUF + 3 * H1_ + j];
                float ig = sigm(zi);
                float fg = sigm(zf);
                float gg = fmaxf(zg, 0.0f);
                float og = sigm(zo);
                c1 = fg * c1 + ig * gg;
                float h = og * fmaxf(c1, 0.0f);
                lds[OFF_H1S + j] = h;
                lds[OFF_H1C + t * H1_ + j] = h;
            }
            __syncthreads();
        }

        // ---- A2: xp2[t][j] = b2[j] + h1_t . W2col_j  (dense) ----
        // xp2 aliases xs/xp1; A1's final barrier guarantees all reads are done.
        {
            #pragma unroll
            for (int k = 0; k < H1_; ++k) wr[k] = W2[k * G2_ + j];
            const float bj = b2[j];
            for (int t = 0; t < TC; ++t) {
                const float4* h4 = (const float4*)&lds[OFF_H1C + t * H1_];
                float acc = bj;
                #pragma unroll
                for (int k = 0; k < H1_ / 4; ++k) {
                    float4 v = h4[k];
                    acc += v.x * wr[4*k] + v.y * wr[4*k+1] + v.z * wr[4*k+2] + v.w * wr[4*k+3];
                }
                lds[OFF_XP2 + t * G2_ + j] = acc;
            }
            // swap in U2 column j
            #pragma unroll
            for (int k = 0; k < H2_; ++k) wr[k] = U2[k * G2_ + j];
        }
        __syncthreads();

        // ---- B: layer-2 recurrence over the chunk ----
        for (int t = 0; t < TC; ++t) {
            {
                float acc = lds[OFF_XP2 + t * G2_ + j];
                const float4* h4 = (const float4*)&lds[OFF_H2S];
                #pragma unroll
                for (int k = 0; k < H2_ / 4; ++k) {
                    float4 v = h4[k];
                    acc += v.x * wr[4*k] + v.y * wr[4*k+1] + v.z * wr[4*k+2] + v.w * wr[4*k+3];
                }
                lds[OFF_ZBUF + j] = acc;
            }
            __syncthreads();
            if (j < H2_) {
                float zi = lds[OFF_ZBUF + j];
                float zf = lds[OFF_ZBUF + H2_ + j];
                float zg = lds[OFF_ZBUF + 2 * H2_ + j];
                float zo = lds[OFF_ZBUF + 3 * H2_ + j];
                float ig = sigm(zi);
                float fg = sigm(zf);
                float gg = fmaxf(zg, 0.0f);
                float og = sigm(zo);
                c2 = fg * c2 + ig * gg;
                float h = og * fmaxf(c2, 0.0f);
                lds[OFF_H2S + j] = h;
            }
            __syncthreads();
        }
    }

    // ---- head: logits = h2_last @ Wd + bd ; softmax over 19 ----
    if (j < OUT_) {
        float acc = bd[j];
        #pragma unroll
        for (int k = 0; k < H2_; ++k) acc += lds[OFF_H2S + k] * Wd[k * OUT_ + j];
        lds[OFF_ZBUF + j] = acc;
    }
    __syncthreads();
    if (j < OUT_) {
        float m = -1e30f;
        for (int k = 0; k < OUT_; ++k) m = fmaxf(m, lds[OFF_ZBUF + k]);
        float s = 0.0f;
        for (int k = 0; k < OUT_; ++k) s += expf(lds[OFF_ZBUF + k] - m);
        out[b * OUT_ + j] = expf(lds[OFF_ZBUF + j] - m) / s;
    }
}

extern "C" void kernel_launch(void* const* d_in, const int* in_sizes, int n_in,
                              void* d_out, int out_size, void* d_ws, size_t ws_size,
                              hipStream_t stream) {
    const float* x  = (const float*)d_in[0];
    const float* W1 = (const float*)d_in[1];
    const float* U1 = (const float*)d_in[2];
    const float* b1 = (const float*)d_in[3];
    const float* W2 = (const float*)d_in[4];
    const float* U2 = (const float*)d_in[5];
    const float* b2 = (const float*)d_in[6];
    const float* Wd = (const float*)d_in[7];
    const float* bd = (const float*)d_in[8];
    float* out = (float*)d_out;

    hipLaunchKernelGGL(lstm_fused, dim3(B_), dim3(512), 0, stream,
                       x, W1, U1, b1, W2, U2, b2, Wd, bd, out);
}

// Round 2
// 3626.848 us; speedup vs baseline: 1.1803x; 1.1803x over previous
//
#include <hip/hip_runtime.h>
#include <math.h>

// Problem dims
#define B_   256
#define T_   512
#define F_   64
#define H1_  100
#define H2_  128
#define OUT_ 19
#define G1_  400   // 4*H1
#define G2_  512   // 4*H2
#define TC   64    // timesteps per chunk
#define NCHUNK (T_/TC)

// ---- LDS layout (in floats) ----
// Union region [0, 32768):
//   during A0/A1: xs[TC*F_]=4096 at 0, xp1[TC*G1_]=25600 at 4096 (ends 29696)
//   during A2/B : xp2[TC*G2_]=32768 at 0
#define OFF_XS    0
#define OFF_XP1   (TC*F_)                 // 4096
#define OFF_XP2   0
#define OFF_H1C   32768                   // TC*H1_ = 6400 floats
#define OFF_ZBUF  (OFF_H1C + TC*H1_)      // 39168, 512 floats
#define OFF_H1S   (OFF_ZBUF + G2_)        // 39680, 128 floats (100 used)
#define OFF_H2S   (OFF_H1S + 128)         // 39808, 128 floats
#define LDS_FLOATS (OFF_H2S + 128)        // 39936 floats = 159744 B (<=163840)

__device__ __forceinline__ float sigm(float x) {
    return 1.0f / (1.0f + __expf(-x));
}

__global__ __launch_bounds__(512) __attribute__((amdgpu_waves_per_eu(2, 2)))
void lstm_fused(
    const float* __restrict__ x,
    const float* __restrict__ W1, const float* __restrict__ U1, const float* __restrict__ b1,
    const float* __restrict__ W2, const float* __restrict__ U2, const float* __restrict__ b2,
    const float* __restrict__ Wd, const float* __restrict__ bd,
    float* __restrict__ out)
{
    __shared__ float lds[LDS_FLOATS];
    const int b = blockIdx.x;
    const int j = threadIdx.x;

    float4 wr4[32];         // per-phase weight column (max 128 floats), const-indexed only
    float c1 = 0.0f;        // cell state, thread k<100 owns c1[k]
    float c2 = 0.0f;        // cell state, thread k<128 owns c2[k]

    if (j < 128) { lds[OFF_H1S + j] = 0.0f; lds[OFF_H2S + j] = 0.0f; }
    __syncthreads();

    const float* xrow = x + (size_t)b * T_ * F_;

    for (int ch = 0; ch < NCHUNK; ++ch) {
        const int t0 = ch * TC;

        // ---- stage x chunk: TC*F_ = 4096 floats = 1024 float4, coalesced ----
        {
            const float4* src4 = (const float4*)(xrow + t0 * F_);
            float4* dst4 = (float4*)&lds[OFF_XS];
            #pragma unroll
            for (int r = 0; r < 2; ++r)
                dst4[r * 512 + j] = src4[r * 512 + j];
        }
        // ---- load W1 column j (coalesced across lanes; const indices) ----
        if (j < G1_) {
            #pragma unroll
            for (int k = 0; k < F_ / 4; ++k) {
                wr4[k].x = W1[(4*k+0) * G1_ + j];
                wr4[k].y = W1[(4*k+1) * G1_ + j];
                wr4[k].z = W1[(4*k+2) * G1_ + j];
                wr4[k].w = W1[(4*k+3) * G1_ + j];
            }
        }
        __syncthreads();   // xs staged; prev chunk's B reads of xp2 done

        // ---- A0: xp1[t][j] = b1[j] + x_t . W1col_j  (dense, barrier-free) ----
        if (j < G1_) {
            const float bj = b1[j];
            for (int t = 0; t < TC; ++t) {
                const float4* xs4 = (const float4*)&lds[OFF_XS + t * F_];
                float a0 = bj, a1 = 0.f, a2 = 0.f, a3 = 0.f;
                #pragma unroll
                for (int k = 0; k < F_ / 4; ++k) {
                    float4 v = xs4[k];
                    a0 += v.x * wr4[k].x;
                    a1 += v.y * wr4[k].y;
                    a2 += v.z * wr4[k].z;
                    a3 += v.w * wr4[k].w;
                }
                lds[OFF_XP1 + t * G1_ + j] = (a0 + a1) + (a2 + a3);
            }
            // swap in U1 column j for the recurrence
            #pragma unroll
            for (int k = 0; k < H1_ / 4; ++k) {
                wr4[k].x = U1[(4*k+0) * G1_ + j];
                wr4[k].y = U1[(4*k+1) * G1_ + j];
                wr4[k].z = U1[(4*k+2) * G1_ + j];
                wr4[k].w = U1[(4*k+3) * G1_ + j];
            }
        }
        __syncthreads();

        // ---- A1: layer-1 recurrence over the chunk ----
        for (int t = 0; t < TC; ++t) {
            if (j < G1_) {
                const float4* h4 = (const float4*)&lds[OFF_H1S];
                float a0 = lds[OFF_XP1 + t * G1_ + j], a1 = 0.f, a2 = 0.f, a3 = 0.f;
                #pragma unroll
                for (int k = 0; k < H1_ / 4; ++k) {
                    float4 v = h4[k];
                    a0 += v.x * wr4[k].x;
                    a1 += v.y * wr4[k].y;
                    a2 += v.z * wr4[k].z;
                    a3 += v.w * wr4[k].w;
                }
                lds[OFF_ZBUF + j] = (a0 + a1) + (a2 + a3);
            }
            __syncthreads();
            if (j < H1_) {
                float zi = lds[OFF_ZBUF + j];
                float zf = lds[OFF_ZBUF + H1_ + j];
                float zg = lds[OFF_ZBUF + 2 * H1_ + j];
                float zo = lds[OFF_ZBUF + 3 * H1_ + j];
                float ig = sigm(zi);
                float fg = sigm(zf);
                float gg = fmaxf(zg, 0.0f);
                float og = sigm(zo);
                c1 = fg * c1 + ig * gg;
                float h = og * fmaxf(c1, 0.0f);
                lds[OFF_H1S + j] = h;
                lds[OFF_H1C + t * H1_ + j] = h;
            }
            __syncthreads();
        }

        // ---- A2: xp2[t][j] = b2[j] + h1_t . W2col_j  (dense) ----
        // xp2 aliases xs/xp1; A1's final barrier guarantees all reads are done.
        {
            #pragma unroll
            for (int k = 0; k < H1_ / 4; ++k) {
                wr4[k].x = W2[(4*k+0) * G2_ + j];
                wr4[k].y = W2[(4*k+1) * G2_ + j];
                wr4[k].z = W2[(4*k+2) * G2_ + j];
                wr4[k].w = W2[(4*k+3) * G2_ + j];
            }
            const float bj = b2[j];
            for (int t = 0; t < TC; ++t) {
                const float4* h4 = (const float4*)&lds[OFF_H1C + t * H1_];
                float a0 = bj, a1 = 0.f, a2 = 0.f, a3 = 0.f;
                #pragma unroll
                for (int k = 0; k < H1_ / 4; ++k) {
                    float4 v = h4[k];
                    a0 += v.x * wr4[k].x;
                    a1 += v.y * wr4[k].y;
                    a2 += v.z * wr4[k].z;
                    a3 += v.w * wr4[k].w;
                }
                lds[OFF_XP2 + t * G2_ + j] = (a0 + a1) + (a2 + a3);
            }
            // swap in U2 column j
            #pragma unroll
            for (int k = 0; k < H2_ / 4; ++k) {
                wr4[k].x = U2[(4*k+0) * G2_ + j];
                wr4[k].y = U2[(4*k+1) * G2_ + j];
                wr4[k].z = U2[(4*k+2) * G2_ + j];
                wr4[k].w = U2[(4*k+3) * G2_ + j];
            }
        }
        __syncthreads();

        // ---- B: layer-2 recurrence over the chunk ----
        for (int t = 0; t < TC; ++t) {
            {
                const float4* h4 = (const float4*)&lds[OFF_H2S];
                float a0 = lds[OFF_XP2 + t * G2_ + j], a1 = 0.f, a2 = 0.f, a3 = 0.f;
                #pragma unroll
                for (int k = 0; k < H2_ / 4; ++k) {
                    float4 v = h4[k];
                    a0 += v.x * wr4[k].x;
                    a1 += v.y * wr4[k].y;
                    a2 += v.z * wr4[k].z;
                    a3 += v.w * wr4[k].w;
                }
                lds[OFF_ZBUF + j] = (a0 + a1) + (a2 + a3);
            }
            __syncthreads();
            if (j < H2_) {
                float zi = lds[OFF_ZBUF + j];
                float zf = lds[OFF_ZBUF + H2_ + j];
                float zg = lds[OFF_ZBUF + 2 * H2_ + j];
                float zo = lds[OFF_ZBUF + 3 * H2_ + j];
                float ig = sigm(zi);
                float fg = sigm(zf);
                float gg = fmaxf(zg, 0.0f);
                float og = sigm(zo);
                c2 = fg * c2 + ig * gg;
                float h = og * fmaxf(c2, 0.0f);
                lds[OFF_H2S + j] = h;
            }
            __syncthreads();
        }
    }

    // ---- head: logits = h2_last @ Wd + bd ; softmax over 19 ----
    if (j < OUT_) {
        float acc = bd[j];
        #pragma unroll
        for (int k = 0; k < H2_; ++k) acc += lds[OFF_H2S + k] * Wd[k * OUT_ + j];
        lds[OFF_ZBUF + j] = acc;
    }
    __syncthreads();
    if (j < OUT_) {
        float m = -1e30f;
        for (int k = 0; k < OUT_; ++k) m = fmaxf(m, lds[OFF_ZBUF + k]);
        float s = 0.0f;
        for (int k = 0; k < OUT_; ++k) s += expf(lds[OFF_ZBUF + k] - m);
        out[b * OUT_ + j] = expf(lds[OFF_ZBUF + j] - m) / s;
    }
}

extern "C" void kernel_launch(void* const* d_in, const int* in_sizes, int n_in,
                              void* d_out, int out_size, void* d_ws, size_t ws_size,
                              hipStream_t stream) {
    const float* x  = (const float*)d_in[0];
    const float* W1 = (const float*)d_in[1];
    const float* U1 = (const float*)d_in[2];
    const float* b1 = (const float*)d_in[3];
    const float* W2 = (const float*)d_in[4];
    const float* U2 = (const float*)d_in[5];
    const float* b2 = (const float*)d_in[6];
    const float* Wd = (const float*)d_in[7];
    const float* bd = (const float*)d_in[8];
    float* out = (float*)d_out;

    hipLaunchKernelGGL(lstm_fused, dim3(B_), dim3(512), 0, stream,
                       x, W1, U1, b1, W2, U2, b2, Wd, bd, out);
}

// Round 3
// 3621.986 us; speedup vs baseline: 1.1818x; 1.0013x over previous
//
#include <hip/hip_runtime.h>
#include <math.h>

// Problem dims
#define B_   256
#define T_   512
#define F_   64
#define H1_  100
#define H2_  128
#define OUT_ 19
#define G1_  400   // 4*H1
#define G2_  512   // 4*H2
#define TC   64    // timesteps per chunk
#define NCHUNK (T_/TC)

// ---- LDS layout (in floats) ----
// Union region [0, 32768):
//   during A0/A1: xs[TC*F_]=4096 at 0, xp1[TC*G1_]=25600 at 4096 (ends 29696)
//   during A2/B : xp2[TC*G2_]=32768 at 0
#define OFF_XS    0
#define OFF_XP1   (TC*F_)                 // 4096
#define OFF_XP2   0
#define OFF_H1C   32768                   // TC*H1_ = 6400 floats
#define OFF_ZBUF  (OFF_H1C + TC*H1_)      // 39168, 512 floats
#define OFF_H1S   (OFF_ZBUF + G2_)        // 39680, 128 floats (100 used)
#define OFF_H2S   (OFF_H1S + 128)         // 39808, 128 floats
#define LDS_FLOATS (OFF_H2S + 128)        // 39936 floats = 159744 B (<=163840)

__device__ __forceinline__ float sigm(float x) {
    return 1.0f / (1.0f + __expf(-x));
}

// NOTE: no __launch_bounds__ — it lowers to its own amdgpu-* attribute set and
// clobbered amdgpu_waves_per_eu in the previous build (VGPR stayed 128 + spills).
// flat_work_group_size(512,512) + waves_per_eu(2,2) => 2048/2 = 256-VGPR budget.
__global__ __attribute__((amdgpu_flat_work_group_size(512, 512), amdgpu_waves_per_eu(2, 2)))
void lstm_fused(
    const float* __restrict__ x,
    const float* __restrict__ W1, const float* __restrict__ U1, const float* __restrict__ b1,
    const float* __restrict__ W2, const float* __restrict__ U2, const float* __restrict__ b2,
    const float* __restrict__ Wd, const float* __restrict__ bd,
    float* __restrict__ out)
{
    __shared__ float lds[LDS_FLOATS];
    const int b = blockIdx.x;
    const int j = threadIdx.x;

    float4 wr4[32];         // per-phase weight column (max 128 floats), const-indexed only
    float c1 = 0.0f;        // cell state, thread k<100 owns c1[k]
    float c2 = 0.0f;        // cell state, thread k<128 owns c2[k]

    if (j < 128) { lds[OFF_H1S + j] = 0.0f; lds[OFF_H2S + j] = 0.0f; }
    __syncthreads();

    const float* xrow = x + (size_t)b * T_ * F_;

    for (int ch = 0; ch < NCHUNK; ++ch) {
        const int t0 = ch * TC;

        // ---- stage x chunk: TC*F_ = 4096 floats = 1024 float4, coalesced ----
        {
            const float4* src4 = (const float4*)(xrow + t0 * F_);
            float4* dst4 = (float4*)&lds[OFF_XS];
            #pragma unroll
            for (int r = 0; r < 2; ++r)
                dst4[r * 512 + j] = src4[r * 512 + j];
        }
        // ---- load W1 column j (coalesced across lanes; const indices) ----
        if (j < G1_) {
            #pragma unroll
            for (int k = 0; k < F_ / 4; ++k) {
                wr4[k].x = W1[(4*k+0) * G1_ + j];
                wr4[k].y = W1[(4*k+1) * G1_ + j];
                wr4[k].z = W1[(4*k+2) * G1_ + j];
                wr4[k].w = W1[(4*k+3) * G1_ + j];
            }
        }
        __syncthreads();   // xs staged; prev chunk's B reads of xp2 done

        // ---- A0: xp1[t][j] = b1[j] + x_t . W1col_j  (dense, barrier-free) ----
        if (j < G1_) {
            const float bj = b1[j];
            for (int t = 0; t < TC; ++t) {
                const float4* xs4 = (const float4*)&lds[OFF_XS + t * F_];
                float a0 = bj, a1 = 0.f, a2 = 0.f, a3 = 0.f;
                #pragma unroll
                for (int k = 0; k < F_ / 4; ++k) {
                    float4 v = xs4[k];
                    a0 += v.x * wr4[k].x;
                    a1 += v.y * wr4[k].y;
                    a2 += v.z * wr4[k].z;
                    a3 += v.w * wr4[k].w;
                }
                lds[OFF_XP1 + t * G1_ + j] = (a0 + a1) + (a2 + a3);
            }
            // swap in U1 column j for the recurrence
            #pragma unroll
            for (int k = 0; k < H1_ / 4; ++k) {
                wr4[k].x = U1[(4*k+0) * G1_ + j];
                wr4[k].y = U1[(4*k+1) * G1_ + j];
                wr4[k].z = U1[(4*k+2) * G1_ + j];
                wr4[k].w = U1[(4*k+3) * G1_ + j];
            }
        }
        __syncthreads();

        // ---- A1: layer-1 recurrence over the chunk ----
        for (int t = 0; t < TC; ++t) {
            if (j < G1_) {
                const float4* h4 = (const float4*)&lds[OFF_H1S];
                float a0 = lds[OFF_XP1 + t * G1_ + j], a1 = 0.f, a2 = 0.f, a3 = 0.f;
                #pragma unroll
                for (int k = 0; k < H1_ / 4; ++k) {
                    float4 v = h4[k];
                    a0 += v.x * wr4[k].x;
                    a1 += v.y * wr4[k].y;
                    a2 += v.z * wr4[k].z;
                    a3 += v.w * wr4[k].w;
                }
                lds[OFF_ZBUF + j] = (a0 + a1) + (a2 + a3);
            }
            __syncthreads();
            if (j < H1_) {
                float zi = lds[OFF_ZBUF + j];
                float zf = lds[OFF_ZBUF + H1_ + j];
                float zg = lds[OFF_ZBUF + 2 * H1_ + j];
                float zo = lds[OFF_ZBUF + 3 * H1_ + j];
                float ig = sigm(zi);
                float fg = sigm(zf);
                float gg = fmaxf(zg, 0.0f);
                float og = sigm(zo);
                c1 = fg * c1 + ig * gg;
                float h = og * fmaxf(c1, 0.0f);
                lds[OFF_H1S + j] = h;
                lds[OFF_H1C + t * H1_ + j] = h;
            }
            __syncthreads();
        }

        // ---- A2: xp2[t][j] = b2[j] + h1_t . W2col_j  (dense) ----
        // xp2 aliases xs/xp1; A1's final barrier guarantees all reads are done.
        {
            #pragma unroll
            for (int k = 0; k < H1_ / 4; ++k) {
                wr4[k].x = W2[(4*k+0) * G2_ + j];
                wr4[k].y = W2[(4*k+1) * G2_ + j];
                wr4[k].z = W2[(4*k+2) * G2_ + j];
                wr4[k].w = W2[(4*k+3) * G2_ + j];
            }
            const float bj = b2[j];
            for (int t = 0; t < TC; ++t) {
                const float4* h4 = (const float4*)&lds[OFF_H1C + t * H1_];
                float a0 = bj, a1 = 0.f, a2 = 0.f, a3 = 0.f;
                #pragma unroll
                for (int k = 0; k < H1_ / 4; ++k) {
                    float4 v = h4[k];
                    a0 += v.x * wr4[k].x;
                    a1 += v.y * wr4[k].y;
                    a2 += v.z * wr4[k].z;
                    a3 += v.w * wr4[k].w;
                }
                lds[OFF_XP2 + t * G2_ + j] = (a0 + a1) + (a2 + a3);
            }
            // swap in U2 column j
            #pragma unroll
            for (int k = 0; k < H2_ / 4; ++k) {
                wr4[k].x = U2[(4*k+0) * G2_ + j];
                wr4[k].y = U2[(4*k+1) * G2_ + j];
                wr4[k].z = U2[(4*k+2) * G2_ + j];
                wr4[k].w = U2[(4*k+3) * G2_ + j];
            }
        }
        __syncthreads();

        // ---- B: layer-2 recurrence over the chunk ----
        for (int t = 0; t < TC; ++t) {
            {
                const float4* h4 = (const float4*)&lds[OFF_H2S];
                float a0 = lds[OFF_XP2 + t * G2_ + j], a1 = 0.f, a2 = 0.f, a3 = 0.f;
                #pragma unroll
                for (int k = 0; k < H2_ / 4; ++k) {
                    float4 v = h4[k];
                    a0 += v.x * wr4[k].x;
                    a1 += v.y * wr4[k].y;
                    a2 += v.z * wr4[k].z;
                    a3 += v.w * wr4[k].w;
                }
                lds[OFF_ZBUF + j] = (a0 + a1) + (a2 + a3);
            }
            __syncthreads();
            if (j < H2_) {
                float zi = lds[OFF_ZBUF + j];
                float zf = lds[OFF_ZBUF + H2_ + j];
                float zg = lds[OFF_ZBUF + 2 * H2_ + j];
                float zo = lds[OFF_ZBUF + 3 * H2_ + j];
                float ig = sigm(zi);
                float fg = sigm(zf);
                float gg = fmaxf(zg, 0.0f);
                float og = sigm(zo);
                c2 = fg * c2 + ig * gg;
                float h = og * fmaxf(c2, 0.0f);
                lds[OFF_H2S + j] = h;
            }
            __syncthreads();
        }
    }

    // ---- head: logits = h2_last @ Wd + bd ; softmax over 19 ----
    if (j < OUT_) {
        float acc = bd[j];
        #pragma unroll
        for (int k = 0; k < H2_; ++k) acc += lds[OFF_H2S + k] * Wd[k * OUT_ + j];
        lds[OFF_ZBUF + j] = acc;
    }
    __syncthreads();
    if (j < OUT_) {
        float m = -1e30f;
        for (int k = 0; k < OUT_; ++k) m = fmaxf(m, lds[OFF_ZBUF + k]);
        float s = 0.0f;
        for (int k = 0; k < OUT_; ++k) s += expf(lds[OFF_ZBUF + k] - m);
        out[b * OUT_ + j] = expf(lds[OFF_ZBUF + j] - m) / s;
    }
}

extern "C" void kernel_launch(void* const* d_in, const int* in_sizes, int n_in,
                              void* d_out, int out_size, void* d_ws, size_t ws_size,
                              hipStream_t stream) {
    const float* x  = (const float*)d_in[0];
    const float* W1 = (const float*)d_in[1];
    const float* U1 = (const float*)d_in[2];
    const float* b1 = (const float*)d_in[3];
    const float* W2 = (const float*)d_in[4];
    const float* U2 = (const float*)d_in[5];
    const float* b2 = (const float*)d_in[6];
    const float* Wd = (const float*)d_in[7];
    const float* bd = (const float*)d_in[8];
    float* out = (float*)d_out;

    hipLaunchKernelGGL(lstm_fused, dim3(B_), dim3(512), 0, stream,
                       x, W1, U1, b1, W2, U2, b2, Wd, bd, out);
}

// Round 4
// 3403.157 us; speedup vs baseline: 1.2578x; 1.0643x over previous
//
#include <hip/hip_runtime.h>
#include <math.h>

// Problem dims
#define B_   256
#define T_   512
#define F_   64
#define H1_  100
#define H2_  128
#define OUT_ 19
#define G1_  400   // 4*H1
#define G2_  512   // 4*H2
#define TC   64    // timesteps per chunk
#define NCHUNK (T_/TC)

// ---- LDS layout (floats) ----
// Union region [0, 32768):
//   during A0/A1: xs[TC*F_]=4096 at 0, xp1[TC*G1_]=25600 at 4096 (ends 29696)
//   during A2/B : xp2[TC*G2_]=32768 at 0
#define OFF_XS    0
#define OFF_XP1   (TC*F_)                 // 4096
#define OFF_XP2   0
#define OFF_H1C   32768                   // TC*H1_ = 6400 floats
#define OFF_ZBUF  (OFF_H1C + TC*H1_)      // 39168, 1024 floats (2 halves x 512)
#define OFF_H1S   (OFF_ZBUF + 1024)       // 40192, 128 floats (100 used)
#define OFF_H2S   (OFF_H1S + 128)         // 40320, 128 floats
#define LDS_FLOATS (OFF_H2S + 128)        // 40448 floats = 161792 B (<=163840)

__device__ __forceinline__ float sigm(float x) {
    return 1.0f / (1.0f + __expf(-x));
}

// 1024 threads = 16 waves = 4 waves/SIMD => hard VGPR cap 128 (pool 512/SIMD).
// Per-thread weight arrays kept to <=16 float4 = 64 VGPRs so nothing spills.
__global__ __launch_bounds__(1024)
void lstm_fused(
    const float* __restrict__ x,
    const float* __restrict__ W1, const float* __restrict__ U1, const float* __restrict__ b1,
    const float* __restrict__ W2, const float* __restrict__ U2, const float* __restrict__ b2,
    const float* __restrict__ Wd, const float* __restrict__ bd,
    float* __restrict__ out)
{
    __shared__ float lds[LDS_FLOATS];
    const int b    = blockIdx.x;
    const int j    = threadIdx.x;
    const int col  = j & 511;
    const int half = j >> 9;

    float4 wr4[16];        // per-phase (half-)weight column, const-indexed only
    float c1 = 0.0f;       // owned by gate thread j<100
    float c2 = 0.0f;       // owned by gate thread j<128

    if (j < 128) { lds[OFF_H1S + j] = 0.0f; lds[OFF_H2S + j] = 0.0f; }
    __syncthreads();

    const float* xrow = x + (size_t)b * T_ * F_;

    for (int ch = 0; ch < NCHUNK; ++ch) {
        // ---- stage x chunk: 4096 floats = 1024 float4, one per thread ----
        ((float4*)&lds[OFF_XS])[j] = ((const float4*)(xrow + ch * TC * F_))[j];

        // ---- load FULL W1 column (64 floats = 16 f4), both halves ----
        if (col < G1_) {
            #pragma unroll
            for (int m = 0; m < 16; ++m) {
                wr4[m].x = W1[(4*m+0) * G1_ + col];
                wr4[m].y = W1[(4*m+1) * G1_ + col];
                wr4[m].z = W1[(4*m+2) * G1_ + col];
                wr4[m].w = W1[(4*m+3) * G1_ + col];
            }
        }
        __syncthreads();   // xs staged; prev chunk's B reads of xp2 done

        // ---- A0: xp1[t][col] = b1 + x_t . W1col ; halves split by t-parity ----
        if (col < G1_) {
            const float bj = b1[col];
            for (int i = 0; i < TC / 2; ++i) {
                const int t = 2 * i + half;
                const float4* xs4 = (const float4*)&lds[OFF_XS + t * F_];
                float a0 = bj, a1 = 0.f, a2 = 0.f, a3 = 0.f;
                #pragma unroll
                for (int m = 0; m < 16; ++m) {
                    float4 v = xs4[m];
                    a0 += v.x * wr4[m].x; a1 += v.y * wr4[m].y;
                    a2 += v.z * wr4[m].z; a3 += v.w * wr4[m].w;
                }
                lds[OFF_XP1 + t * G1_ + col] = (a0 + a1) + (a2 + a3);
            }
            // ---- load U1 HALF-column: half0 rows 0..47 (12 f4), half1 rows 48..99 (13 f4)
            if (half == 0) {
                #pragma unroll
                for (int m = 0; m < 12; ++m) {
                    wr4[m].x = U1[(4*m+0) * G1_ + col];
                    wr4[m].y = U1[(4*m+1) * G1_ + col];
                    wr4[m].z = U1[(4*m+2) * G1_ + col];
                    wr4[m].w = U1[(4*m+3) * G1_ + col];
                }
            } else {
                #pragma unroll
                for (int m = 0; m < 13; ++m) {
                    wr4[m].x = U1[(48+4*m+0) * G1_ + col];
                    wr4[m].y = U1[(48+4*m+1) * G1_ + col];
                    wr4[m].z = U1[(48+4*m+2) * G1_ + col];
                    wr4[m].w = U1[(48+4*m+3) * G1_ + col];
                }
            }
        }
        __syncthreads();   // xp1 complete

        // ---- A1: layer-1 recurrence, k-split halves ----
        for (int t = 0; t < TC; ++t) {
            if (col < G1_) {
                float a0, a1 = 0.f, a2 = 0.f, a3 = 0.f;
                if (half == 0) {
                    a0 = lds[OFF_XP1 + t * G1_ + col];   // seed with xproj
                    const float4* h4 = (const float4*)&lds[OFF_H1S];
                    #pragma unroll
                    for (int m = 0; m < 12; ++m) {
                        float4 v = h4[m];
                        a0 += v.x * wr4[m].x; a1 += v.y * wr4[m].y;
                        a2 += v.z * wr4[m].z; a3 += v.w * wr4[m].w;
                    }
                } else {
                    a0 = 0.f;
                    const float4* h4 = (const float4*)&lds[OFF_H1S + 48];
                    #pragma unroll
                    for (int m = 0; m < 13; ++m) {
                        float4 v = h4[m];
                        a0 += v.x * wr4[m].x; a1 += v.y * wr4[m].y;
                        a2 += v.z * wr4[m].z; a3 += v.w * wr4[m].w;
                    }
                }
                lds[OFF_ZBUF + half * 512 + col] = (a0 + a1) + (a2 + a3);
            }
            __syncthreads();
            if (j < H1_) {
                float zi = lds[OFF_ZBUF + j]           + lds[OFF_ZBUF + 512 + j];
                float zf = lds[OFF_ZBUF + H1_ + j]     + lds[OFF_ZBUF + 512 + H1_ + j];
                float zg = lds[OFF_ZBUF + 2*H1_ + j]   + lds[OFF_ZBUF + 512 + 2*H1_ + j];
                float zo = lds[OFF_ZBUF + 3*H1_ + j]   + lds[OFF_ZBUF + 512 + 3*H1_ + j];
                float ig = sigm(zi);
                float fg = sigm(zf);
                float gg = fmaxf(zg, 0.0f);
                float og = sigm(zo);
                c1 = fg * c1 + ig * gg;
                float h = og * fmaxf(c1, 0.0f);
                lds[OFF_H1S + j] = h;
                lds[OFF_H1C + t * H1_ + j] = h;
            }
            __syncthreads();
        }

        // ---- load W2 HALF-column ----
        if (half == 0) {
            #pragma unroll
            for (int m = 0; m < 12; ++m) {
                wr4[m].x = W2[(4*m+0) * G2_ + col];
                wr4[m].y = W2[(4*m+1) * G2_ + col];
                wr4[m].z = W2[(4*m+2) * G2_ + col];
                wr4[m].w = W2[(4*m+3) * G2_ + col];
            }
        } else {
            #pragma unroll
            for (int m = 0; m < 13; ++m) {
                wr4[m].x = W2[(48+4*m+0) * G2_ + col];
                wr4[m].y = W2[(48+4*m+1) * G2_ + col];
                wr4[m].z = W2[(48+4*m+2) * G2_ + col];
                wr4[m].w = W2[(48+4*m+3) * G2_ + col];
            }
        }

        // ---- A2 pass A (half 0): xp2 = b2 + h1c[t][0:48] . W2 ----
        if (half == 0) {
            const float bj = b2[col];
            for (int t = 0; t < TC; ++t) {
                const float4* h4 = (const float4*)&lds[OFF_H1C + t * H1_];
                float a0 = bj, a1 = 0.f, a2 = 0.f, a3 = 0.f;
                #pragma unroll
                for (int m = 0; m < 12; ++m) {
                    float4 v = h4[m];
                    a0 += v.x * wr4[m].x; a1 += v.y * wr4[m].y;
                    a2 += v.z * wr4[m].z; a3 += v.w * wr4[m].w;
                }
                lds[OFF_XP2 + t * G2_ + col] = (a0 + a1) + (a2 + a3);
            }
        }
        __syncthreads();
        // ---- A2 pass B (half 1): xp2 += h1c[t][48:100] . W2 ----
        if (half == 1) {
            for (int t = 0; t < TC; ++t) {
                const float4* h4 = (const float4*)&lds[OFF_H1C + t * H1_ + 48];
                float a0 = 0.f, a1 = 0.f, a2 = 0.f, a3 = 0.f;
                #pragma unroll
                for (int m = 0; m < 13; ++m) {
                    float4 v = h4[m];
                    a0 += v.x * wr4[m].x; a1 += v.y * wr4[m].y;
                    a2 += v.z * wr4[m].z; a3 += v.w * wr4[m].w;
                }
                lds[OFF_XP2 + t * G2_ + col] += (a0 + a1) + (a2 + a3);
            }
        }
        // ---- load U2 HALF-column (16 f4): half h covers rows 64h..64h+63 ----
        {
            #pragma unroll
            for (int m = 0; m < 16; ++m) {
                wr4[m].x = U2[(64*half + 4*m+0) * G2_ + col];
                wr4[m].y = U2[(64*half + 4*m+1) * G2_ + col];
                wr4[m].z = U2[(64*half + 4*m+2) * G2_ + col];
                wr4[m].w = U2[(64*half + 4*m+3) * G2_ + col];
            }
        }
        __syncthreads();   // xp2 complete

        // ---- B: layer-2 recurrence, k-split halves ----
        for (int t = 0; t < TC; ++t) {
            {
                const float4* h4 = (const float4*)&lds[OFF_H2S + 64 * half];
                float a0 = (half == 0) ? lds[OFF_XP2 + t * G2_ + col] : 0.f;
                float a1 = 0.f, a2 = 0.f, a3 = 0.f;
                #pragma unroll
                for (int m = 0; m < 16; ++m) {
                    float4 v = h4[m];
                    a0 += v.x * wr4[m].x; a1 += v.y * wr4[m].y;
                    a2 += v.z * wr4[m].z; a3 += v.w * wr4[m].w;
                }
                lds[OFF_ZBUF + half * 512 + col] = (a0 + a1) + (a2 + a3);
            }
            __syncthreads();
            if (j < H2_) {
                float zi = lds[OFF_ZBUF + j]           + lds[OFF_ZBUF + 512 + j];
                float zf = lds[OFF_ZBUF + H2_ + j]     + lds[OFF_ZBUF + 512 + H2_ + j];
                float zg = lds[OFF_ZBUF + 2*H2_ + j]   + lds[OFF_ZBUF + 512 + 2*H2_ + j];
                float zo = lds[OFF_ZBUF + 3*H2_ + j]   + lds[OFF_ZBUF + 512 + 3*H2_ + j];
                float ig = sigm(zi);
                float fg = sigm(zf);
                float gg = fmaxf(zg, 0.0f);
                float og = sigm(zo);
                c2 = fg * c2 + ig * gg;
                float h = og * fmaxf(c2, 0.0f);
                lds[OFF_H2S + j] = h;
            }
            __syncthreads();
        }
    }

    // ---- head: logits = h2_last @ Wd + bd ; softmax over 19 ----
    if (j < OUT_) {
        float acc = bd[j];
        #pragma unroll
        for (int k = 0; k < H2_; ++k) acc += lds[OFF_H2S + k] * Wd[k * OUT_ + j];
        lds[OFF_ZBUF + j] = acc;
    }
    __syncthreads();
    if (j < OUT_) {
        float m = -1e30f;
        for (int k = 0; k < OUT_; ++k) m = fmaxf(m, lds[OFF_ZBUF + k]);
        float s = 0.0f;
        for (int k = 0; k < OUT_; ++k) s += expf(lds[OFF_ZBUF + k] - m);
        out[b * OUT_ + j] = expf(lds[OFF_ZBUF + j] - m) / s;
    }
}

extern "C" void kernel_launch(void* const* d_in, const int* in_sizes, int n_in,
                              void* d_out, int out_size, void* d_ws, size_t ws_size,
                              hipStream_t stream) {
    const float* x  = (const float*)d_in[0];
    const float* W1 = (const float*)d_in[1];
    const float* U1 = (const float*)d_in[2];
    const float* b1 = (const float*)d_in[3];
    const float* W2 = (const float*)d_in[4];
    const float* U2 = (const float*)d_in[5];
    const float* b2 = (const float*)d_in[6];
    const float* Wd = (const float*)d_in[7];
    const float* bd = (const float*)d_in[8];
    float* out = (float*)d_out;

    hipLaunchKernelGGL(lstm_fused, dim3(B_), dim3(1024), 0, stream,
                       x, W1, U1, b1, W2, U2, b2, Wd, bd, out);
}